// Round 3
// baseline (589.993 us; speedup 1.0000x reference)
//
#include <hip/hip_runtime.h>
#include <math.h>

// Problem constants
#define B_    64
#define MAXT  511
#define TP1   512
#define S_    1024
#define H_    4096
#define M_TOTAL (B_*TP1)   // 32768 rows
#define NT    (S_/64)      // 16 K-tiles of BK=64

typedef __attribute__((ext_vector_type(8))) short  short8;   // 8 bf16 (MFMA A/B frag)
typedef __attribute__((ext_vector_type(4))) float  float4v;  // MFMA C/D frag

// ---- workspace layout (bytes) ----
#define ZBUF_BYTES ((size_t)M_TOTAL*4*sizeof(float))   // 524288
#define SBF_OFF    0x81000                             // 528384 >= ZBUF_BYTES
#define SBF_BYTES  ((size_t)M_TOTAL*S_*2)
#define W1T_OFF    (SBF_OFF + SBF_BYTES)

static __device__ __forceinline__ unsigned short f2bf(float f) {
    unsigned int u = __float_as_uint(f);
    u = u + 0x7fffu + ((u >> 16) & 1u);   // round-to-nearest-even
    return (unsigned short)(u >> 16);
}

// ---- merged pre-pass (unchanged from 471us baseline) ----
__global__ __launch_bounds__(256) void prep_kernel(const float* __restrict__ s,
                                                   const float* __restrict__ W1,
                                                   const int*   __restrict__ lengths,
                                                   unsigned short* __restrict__ Sb,
                                                   unsigned short* __restrict__ W1T) {
    int bid = blockIdx.x;
    if (bid < 16384) {
        int row = 2 * bid + (threadIdx.x >> 7);
        int b = row >> 9, t = row & 511;
        if (t >= lengths[b]) return;
        size_t idx = (size_t)row * S_ + (threadIdx.x & 127) * 8;
        float4v f0 = __builtin_nontemporal_load((const float4v*)(s + idx));
        float4v f1 = __builtin_nontemporal_load((const float4v*)(s + idx + 4));
        short8 o;
        o[0] = (short)f2bf(f0[0]); o[1] = (short)f2bf(f0[1]);
        o[2] = (short)f2bf(f0[2]); o[3] = (short)f2bf(f0[3]);
        o[4] = (short)f2bf(f1[0]); o[5] = (short)f2bf(f1[1]);
        o[6] = (short)f2bf(f1[2]); o[7] = (short)f2bf(f1[3]);
        *(short8*)(Sb + idx) = o;
    } else {
        __shared__ float tile[32][33];
        int tb = bid - 16384;
        int h0 = (tb & 127) * 32;
        int k0 = (tb >> 7) * 32;
        int tx = threadIdx.x & 31, ty = threadIdx.x >> 5;
        for (int r = ty; r < 32; r += 8)
            tile[r][tx] = __builtin_nontemporal_load(&W1[(size_t)(k0 + r) * H_ + h0 + tx]);
        __syncthreads();
        for (int r = ty; r < 32; r += 8)
            W1T[(size_t)(h0 + r) * S_ + k0 + tx] = f2bf(tile[tx][r]);
    }
}

// ---- main fused GEMM: 256x256 tile, BK=64, 8-phase DEEP counted-vmcnt ----
// Round-2 post-mortem fixes:
//  (a) stage depth: BOTH operands staged 2 K-tiles ahead at their earliest
//      legal slots -- B(t+2) at ph3 (buf[bb].B reads complete at ph2, proven
//      across waves by the double-barrier phase structure), A(t+2) at ph4
//      (buf[bb].A reads complete at ph3). One vmcnt(8) per K-tile; the
//      youngest load it retires is a full tile (~4 phases) old.
//      Round-2's ledger retired loads issued only 2 phases earlier -> every
//      wave stalled ~500cy/K-tile -> MfmaUtil 20%.
//  (b) XCD map: ntile INNERmost (mtile=sl>>1, ntile=xcd*2+(sl&1)) so adjacent
//      co-resident blocks share the 512KB A-panel in L2 and each XCD reads
//      live-A once (round-2 read it twice: FETCH 230->428MB).
// vmcnt ledger (steady, end of tile t): queue oldest->youngest =
//   [B(t+1)x4 @ph3(t-1), A(t+1)x4 @ph4(t-1), B(t+2)x4 @ph3(t), A(t+2)x4 @ph4(t)]
// vmcnt(8) retires the 8 oldest = tile t+1 resident. Prologue: 16 loads
// (tiles 0,1), vmcnt(8) = tile 0 resident. t==NT-2: vmcnt(0) drains the rest.
typedef __attribute__((address_space(1))) unsigned int gu32;
typedef __attribute__((address_space(3))) unsigned int lu32;
static __device__ __forceinline__ void gload16(const void* g, void* l) {
    __builtin_amdgcn_global_load_lds((gu32*)g, (lu32*)l, 16, 0, 0);
}
static __device__ __forceinline__ short8 ld8(const char* p) { return *(const short8*)p; }

__global__ __launch_bounds__(512, 2) void gemm_fused_kernel(
        const unsigned short* __restrict__ Sb,    // M x S bf16
        const unsigned short* __restrict__ W1T,   // H x S bf16
        const float* __restrict__ b1,             // H
        const float* __restrict__ W2,             // H x 32 fp32 (cols 0..3 used)
        const int*   __restrict__ lengths,        // B
        float*       __restrict__ zbuf)           // M x 4
{
    // XCD-swizzled grid: xcd owns 2 n-panels; ntile varies fastest within XCD
    int id  = blockIdx.x;
    int xcd = id & 7;
    int sl  = id >> 3;                 // 0..255
    int mtile = sl >> 1;               // 0..127 (outer within XCD)
    int ntile = xcd * 2 + (sl & 1);    // 0..15  (inner: A-panel L2 reuse)
    int bi = mtile >> 1;
    if (lengths[bi] <= (mtile & 1) * 256) return;   // whole 256-row tile dead (uniform)
    int m0 = mtile * 256;
    int n0 = ntile * 256;

    __shared__ unsigned short lds[2][2][16384];   // [buf][A|B][32 KB] = 128 KiB
    char* L = (char*)lds;

    int tid = threadIdx.x;
    int wid = tid >> 6, lane = tid & 63;
    int lane15 = lane & 15, quad = lane >> 4;
    int wave_m = (wid >> 2) * 128;     // 0 / 128
    int wave_n = (wid & 3) * 64;       // 0 / 64 / 128 / 192

    // fragment-read addressing (rows of 128 B = BK*2; swizzle bits 4..6)
    int smask = (lane15 & 7) << 4;
    int c0 = (quad * 16) ^ smask;          // k-chunk byte for kk=0
    int c1 = (64 + quad * 16) ^ smask;     // kk=1
    int aRow = (wave_m + lane15) * 128;
    int bRow = (wave_n + lane15) * 128;

    // staging: per-thread inverse-swizzled global source; linear LDS dest
    int srow = tid >> 3;                                    // 0..63
    int scol = ((tid & 7) * 16) ^ ((srow & 7) << 4);
    const char* gAs = (const char*)Sb  + (size_t)(m0 + srow) * 2048 + scol;
    const char* gBs = (const char*)W1T + (size_t)(n0 + srow) * 2048 + scol;
    char* dA = L + wid * 1024;             // + bb*65536 + h*16384 (+8192 for issue 1)
    char* dB = L + 32768 + wid * 1024;

#define STAGE_A(bb,h,tt) do { \
    const char* g_ = gAs + (h)*262144 + (tt)*128; \
    char* d_ = dA + (bb)*65536 + (h)*16384; \
    gload16(g_, d_); gload16(g_ + 131072, d_ + 8192); } while(0)
#define STAGE_B(bb,h,tt) do { \
    const char* g_ = gBs + (h)*262144 + (tt)*128; \
    char* d_ = dB + (bb)*65536 + (h)*16384; \
    gload16(g_, d_); gload16(g_ + 131072, d_ + 8192); } while(0)

    float4v acc[8][4] = {};
    short8 af[4][2], bfr[4][2];

    // prologue: tiles 0 and 1 fully staged (16 loads); wait oldest 8 = tile 0
    STAGE_B(0,0,0); STAGE_B(0,1,0); STAGE_A(0,0,0); STAGE_A(0,1,0);
    STAGE_B(1,0,1); STAGE_B(1,1,1); STAGE_A(1,0,1); STAGE_A(1,1,1);
    asm volatile("s_waitcnt vmcnt(8)" ::: "memory");
    __builtin_amdgcn_sched_barrier(0);
    __builtin_amdgcn_s_barrier();

#define MFMA16(MH, NF0) \
    _Pragma("unroll") for (int mf = 0; mf < 4; ++mf) \
    _Pragma("unroll") for (int nf = 0; nf < 2; ++nf) \
    _Pragma("unroll") for (int kk = 0; kk < 2; ++kk) \
        acc[(MH)*4+mf][(NF0)+nf] = __builtin_amdgcn_mfma_f32_16x16x32_bf16( \
            af[mf][kk], bfr[(NF0)+nf][kk], acc[(MH)*4+mf][(NF0)+nf], 0, 0, 0)

#define PH_BEGIN() \
    __builtin_amdgcn_s_barrier(); \
    asm volatile("s_waitcnt lgkmcnt(0)" ::: "memory"); \
    __builtin_amdgcn_sched_barrier(0); \
    __builtin_amdgcn_s_setprio(1)
#define PH_END() \
    __builtin_amdgcn_s_setprio(0); \
    __builtin_amdgcn_sched_barrier(0); \
    __builtin_amdgcn_s_barrier()

#pragma unroll 2
    for (int t = 0; t < NT; ++t) {
        int bb = t & 1;
        const char* A  = L + bb * 65536;
        const char* Bm = A + 32768;
        // ---- phase 1: (mh0, nh0) -- 12 ds_read_b128, no staging ----
#pragma unroll
        for (int mf = 0; mf < 4; ++mf) {
            af[mf][0] = ld8(A + aRow + mf*2048 + c0);
            af[mf][1] = ld8(A + aRow + mf*2048 + c1);
        }
#pragma unroll
        for (int nf = 0; nf < 2; ++nf) {
            bfr[nf][0] = ld8(Bm + bRow + nf*2048 + c0);
            bfr[nf][1] = ld8(Bm + bRow + nf*2048 + c1);
        }
        PH_BEGIN();
        MFMA16(0, 0);
        PH_END();
        // ---- phase 2: (mh0, nh1) -- 4 ds_read_b128, no staging ----
#pragma unroll
        for (int nf = 2; nf < 4; ++nf) {
            bfr[nf][0] = ld8(Bm + bRow + nf*2048 + c0);
            bfr[nf][1] = ld8(Bm + bRow + nf*2048 + c1);
        }
        PH_BEGIN();
        MFMA16(0, 2);
        PH_END();
        // ---- phase 3: (mh1, nh1) -- 8 ds_read_b128; stage B(t+2) -> buf[bb].B
        //      (buf[bb].B reads completed at ph2's lgkm drain, all waves) ----
#pragma unroll
        for (int mf = 0; mf < 4; ++mf) {
            af[mf][0] = ld8(A + aRow + 8192 + mf*2048 + c0);
            af[mf][1] = ld8(A + aRow + 8192 + mf*2048 + c1);
        }
        if (t + 2 < NT) { STAGE_B(bb, 0, t+2); STAGE_B(bb, 1, t+2); }
        PH_BEGIN();
        MFMA16(1, 2);
        PH_END();
        // ---- phase 4: stage A(t+2) -> buf[bb].A (reads completed at ph3);
        //      MFMA; ONE counted vmcnt(8) per K-tile, never 0 mid-loop ----
        if (t + 2 < NT) { STAGE_A(bb, 0, t+2); STAGE_A(bb, 1, t+2); }
        __builtin_amdgcn_s_barrier();
        __builtin_amdgcn_sched_barrier(0);
        __builtin_amdgcn_s_setprio(1);
        MFMA16(1, 0);
        __builtin_amdgcn_s_setprio(0);
        __builtin_amdgcn_sched_barrier(0);
        if (t < NT - 2)       { asm volatile("s_waitcnt vmcnt(8)" ::: "memory"); __builtin_amdgcn_sched_barrier(0); }
        else if (t == NT - 2) { asm volatile("s_waitcnt vmcnt(0)" ::: "memory"); __builtin_amdgcn_sched_barrier(0); }
        __builtin_amdgcn_s_barrier();
    }

    // ---- fused epilogue: relu(h) @ W2[:,0:4], shuffle-reduce, atomicAdd ----
    float4v w2r[4];
    float   b1v[4];
#pragma unroll
    for (int nf = 0; nf < 4; ++nf) {
        int n_g = n0 + wave_n + nf * 16 + lane15;
        w2r[nf] = *(const float4v*)(W2 + (size_t)n_g * 32);
        b1v[nf] = b1[n_g];
    }
#pragma unroll
    for (int ms = 0; ms < 8; ++ms) {
        float p[4][4];
#pragma unroll
        for (int r = 0; r < 4; ++r)
#pragma unroll
            for (int c = 0; c < 4; ++c) p[r][c] = 0.f;
#pragma unroll
        for (int nf = 0; nf < 4; ++nf) {
            float4v av = acc[ms][nf];
#pragma unroll
            for (int r = 0; r < 4; ++r) {
                float h = av[r] + b1v[nf];
                h = h > 0.f ? h : 0.f;
                p[r][0] += h * w2r[nf][0];
                p[r][1] += h * w2r[nf][1];
                p[r][2] += h * w2r[nf][2];
                p[r][3] += h * w2r[nf][3];
            }
        }
#pragma unroll
        for (int off = 1; off < 16; off <<= 1)
#pragma unroll
            for (int r = 0; r < 4; ++r)
#pragma unroll
                for (int c = 0; c < 4; ++c)
                    p[r][c] += __shfl_xor(p[r][c], off);
        if (lane15 < 4) {
            int c = lane15;
#pragma unroll
            for (int r = 0; r < 4; ++r) {
                int mg = m0 + wave_m + ms * 16 + quad * 4 + r;
                atomicAdd(&zbuf[(size_t)mg * 4 + c], p[r][c]);
            }
        }
    }
#undef STAGE_A
#undef STAGE_B
#undef MFMA16
#undef PH_BEGIN
#undef PH_END
}

// ---- log-softmax gather + masked sum (unchanged) ----
__global__ __launch_bounds__(128) void reduce_logp_kernel(
        const float* __restrict__ zbuf,
        const int*   __restrict__ actions,
        const int*   __restrict__ lengths,
        const float* __restrict__ b2,
        float*       __restrict__ out)
{
    int b = blockIdx.x;
    int t = blockIdx.y * 128 + threadIdx.x;
    int len = lengths[b];
    float local = 0.f;
    if (t < MAXT && t < len) {
        int row = b * TP1 + t;
        float4v z = *(const float4v*)(zbuf + (size_t)row * 4);
        float z0 = z[0] + b2[0], z1 = z[1] + b2[1], z2 = z[2] + b2[2], z3 = z[3] + b2[3];
        float mx = fmaxf(fmaxf(z0, z1), fmaxf(z2, z3));
        float se = expf(z0 - mx) + expf(z1 - mx) + expf(z2 - mx) + expf(z3 - mx);
        int a = actions[b * MAXT + t];
        float za = (a == 0) ? z0 : (a == 1) ? z1 : (a == 2) ? z2 : z3;
        local = (za - mx) - logf(se);
    }
#pragma unroll
    for (int off = 32; off > 0; off >>= 1) local += __shfl_xor(local, off);
    __shared__ float wsum[2];
    if ((threadIdx.x & 63) == 0) wsum[threadIdx.x >> 6] = local;
    __syncthreads();
    if (threadIdx.x == 0) atomicAdd(out, -(wsum[0] + wsum[1]));
}

extern "C" void kernel_launch(void* const* d_in, const int* in_sizes, int n_in,
                              void* d_out, int out_size, void* d_ws, size_t ws_size,
                              hipStream_t stream) {
    const float* s       = (const float*)d_in[0];  // (64,512,1024) fp32
    const int*   actions = (const int*)  d_in[1];  // (64,511)
    const int*   lengths = (const int*)  d_in[2];  // (64,)
    const float* W1      = (const float*)d_in[3];  // (1024,4096)
    const float* b1      = (const float*)d_in[4];  // (4096,)
    const float* W2      = (const float*)d_in[5];  // (4096,32)
    const float* b2      = (const float*)d_in[6];  // (32,)

    char* ws = (char*)d_ws;
    float*          zbuf = (float*)ws;             // [0, 512KB)
    unsigned short* Sb   = (unsigned short*)(ws + SBF_OFF);
    unsigned short* W1T  = (unsigned short*)(ws + W1T_OFF);

    hipMemsetAsync(ws, 0, ZBUF_BYTES, stream);
    hipMemsetAsync(d_out, 0, sizeof(float), stream);

    // merged pre-pass: s->bf16 (live rows, nt loads) + W1->W1T bf16
    prep_kernel<<<dim3(16384 + 4096), 256, 0, stream>>>(s, W1, lengths, Sb, W1T);
    // 256x256 deep-pipelined 8-phase fused GEMM + relu + W2[:,0:4] projection
    gemm_fused_kernel<<<dim3(2048), 512, 0, stream>>>(Sb, W1T, b1, W2, lengths, zbuf);
    // log-softmax gather + masked sum -> d_out
    reduce_logp_kernel<<<dim3(B_, 4), 128, 0, stream>>>(zbuf, actions, lengths, b2, (float*)d_out);
}

// Round 4
// 486.284 us; speedup vs baseline: 1.2133x; 1.2133x over previous
//
#include <hip/hip_runtime.h>
#include <math.h>

// Problem constants
#define B_    64
#define MAXT  511
#define TP1   512
#define S_    1024
#define H_    4096
#define M_TOTAL (B_*TP1)   // 32768 rows
#define NITER (S_/32)      // 32 K-iterations of BK=32

typedef __attribute__((ext_vector_type(8))) short  short8;   // 8 bf16 (MFMA A/B frag)
typedef __attribute__((ext_vector_type(4))) float  float4v;  // MFMA C/D frag

// ---- workspace layout (bytes) ----
#define ZBUF_BYTES ((size_t)M_TOTAL*4*sizeof(float))   // 524288
#define SBF_OFF    0x81000                             // 528384 >= ZBUF_BYTES
#define SBF_BYTES  ((size_t)M_TOTAL*S_*2)
#define W1T_OFF    (SBF_OFF + SBF_BYTES)

static __device__ __forceinline__ unsigned short f2bf(float f) {
    unsigned int u = __float_as_uint(f);
    u = u + 0x7fffu + ((u >> 16) & 1u);   // round-to-nearest-even
    return (unsigned short)(u >> 16);
}

// ---- merged pre-pass (unchanged from 471us baseline) ----
__global__ __launch_bounds__(256) void prep_kernel(const float* __restrict__ s,
                                                   const float* __restrict__ W1,
                                                   const int*   __restrict__ lengths,
                                                   unsigned short* __restrict__ Sb,
                                                   unsigned short* __restrict__ W1T) {
    int bid = blockIdx.x;
    if (bid < 16384) {
        int row = 2 * bid + (threadIdx.x >> 7);
        int b = row >> 9, t = row & 511;
        if (t >= lengths[b]) return;
        size_t idx = (size_t)row * S_ + (threadIdx.x & 127) * 8;
        float4v f0 = __builtin_nontemporal_load((const float4v*)(s + idx));
        float4v f1 = __builtin_nontemporal_load((const float4v*)(s + idx + 4));
        short8 o;
        o[0] = (short)f2bf(f0[0]); o[1] = (short)f2bf(f0[1]);
        o[2] = (short)f2bf(f0[2]); o[3] = (short)f2bf(f0[3]);
        o[4] = (short)f2bf(f1[0]); o[5] = (short)f2bf(f1[1]);
        o[6] = (short)f2bf(f1[2]); o[7] = (short)f2bf(f1[3]);
        *(short8*)(Sb + idx) = o;
    } else {
        __shared__ float tile[32][33];
        int tb = bid - 16384;
        int h0 = (tb & 127) * 32;
        int k0 = (tb >> 7) * 32;
        int tx = threadIdx.x & 31, ty = threadIdx.x >> 5;
        for (int r = ty; r < 32; r += 8)
            tile[r][tx] = __builtin_nontemporal_load(&W1[(size_t)(k0 + r) * H_ + h0 + tx]);
        __syncthreads();
        for (int r = ty; r < 32; r += 8)
            W1T[(size_t)(h0 + r) * S_ + k0 + tx] = f2bf(tile[tx][r]);
    }
}

// ---- main fused GEMM: PROVEN 287us structure + global_load_lds staging ----
// Round-3 post-mortem: the 8-phase 256^2 port is in m232's "not reproduced"
// bucket (MfmaUtil stuck at 20-21% across two ledger variants; at 1 block/CU
// there is no TLP to mask the residual serialization). Reverting to the
// verified 128^2 / BK=32 / 2-phase structure and applying the ONE change with
// direct A/B evidence at this tile size: reg-staging -> global_load_lds w=16
// (m151: 646->874 TF at 128^2, +35%; m193: width 16 vs 4 = +67%).
//  - same chunk map as baseline: chunk c -> row m=c>>2, slot cp=c&3, global
//    k-chunk q = cp ^ ((m>>1)&3) (XOR swizzle). gload_lds writes linearly
//    (dest = base + lane*16, our layout IS linear in tid) and the swizzle is
//    pre-applied to the GLOBAL source address -> both-sides-or-neither rule.
//  - dropping the 12 short8 staging regs (~48 VGPR) allows (256,4):
//    4 blocks/CU (LDS 32KB*4=128KB), restoring the cross-block overlap the
//    m97 structure relies on (m114).
//  - __syncthreads at iter end drains the just-issued next-buf loads
//    (compiler emits vmcnt(0) before s_barrier) -- the documented ~20% m97
//    stall, masked by 4-block TLP.
typedef __attribute__((address_space(1))) unsigned int gu32;
typedef __attribute__((address_space(3))) unsigned int lu32;
static __device__ __forceinline__ void gload16(const void* g, void* l) {
    __builtin_amdgcn_global_load_lds((gu32*)g, (lu32*)l, 16, 0, 0);
}

__global__ __launch_bounds__(256, 4) void gemm_fused_kernel(
        const unsigned short* __restrict__ Sb,    // M x S bf16
        const unsigned short* __restrict__ W1T,   // H x S bf16
        const float* __restrict__ b1,             // H
        const float* __restrict__ W2,             // H x 32 fp32 (cols 0..3 used)
        const int*   __restrict__ lengths,        // B
        float*       __restrict__ zbuf)           // M x 4
{
    int id   = blockIdx.x;
    int xcd  = id & 7;
    int slot = id >> 3;                  // 0..1023
    int ntile = xcd * 4 + (slot & 3);    // 0..31 (inner: A-panel L2 reuse)
    int mtile = slot >> 2;               // 0..255

    int b  = mtile >> 2;
    int t0 = (mtile & 3) * 128;
    if (lengths[b] <= t0) return;        // whole 128-row tile masked out (uniform)

    int m0 = mtile * 128;
    int n0 = ntile * 128;

    __shared__ unsigned short smemA[2 * 128 * 32];   // 2 x 8 KB
    __shared__ unsigned short smemB[2 * 128 * 32];   // 2 x 8 KB

    int tid  = threadIdx.x;
    int wid  = tid >> 6;
    int lane = tid & 63;
    int lane15 = lane & 15;
    int quad   = lane >> 4;
    int wave_m = (wid >> 1) * 64;
    int wave_n = (wid & 1) * 64;

    // staging chunk map: chunk c -> row m=c>>2, slot cp=c&3, global k-chunk
    // q = cp ^ ((m>>1)&3)  (XOR swizzle, involution; LDS stays linear)
    int cA0 = tid, cA1 = tid + 256;
    int mA0 = cA0 >> 2, q0 = (cA0 & 3) ^ ((mA0 >> 1) & 3);
    int mA1 = cA1 >> 2, q1 = (cA1 & 3) ^ ((mA1 >> 1) & 3);

    const char* gA0 = (const char*)Sb  + (size_t)(m0 + mA0) * (S_*2) + q0 * 16;
    const char* gA1 = (const char*)Sb  + (size_t)(m0 + mA1) * (S_*2) + q1 * 16;
    const char* gB0 = (const char*)W1T + (size_t)(n0 + mA0) * (S_*2) + q0 * 16;
    const char* gB1 = (const char*)W1T + (size_t)(n0 + mA1) * (S_*2) + q1 * 16;
    char* lwA0 = (char*)smemA + cA0 * 16;   // buf0 write addrs; buf1 = +8192
    char* lwA1 = (char*)smemA + cA1 * 16;
    char* lwB0 = (char*)smemB + cA0 * 16;
    char* lwB1 = (char*)smemB + cA1 * 16;

    // fragment read offsets within a buffer (in shorts) -- measured 0 conflicts
    int aOff[4], bOff[4];
#pragma unroll
    for (int s = 0; s < 4; s++) {
        int ml = wave_m + s * 16 + lane15;
        aOff[s] = ml * 32 + (quad ^ ((ml >> 1) & 3)) * 8;
        int nl = wave_n + s * 16 + lane15;
        bOff[s] = nl * 32 + (quad ^ ((nl >> 1) & 3)) * 8;
    }

#define STAGE(bufsel, jj) do { \
    int off_ = (jj) * 64; int lb_ = (bufsel) * 8192; \
    gload16(gA0 + off_, lwA0 + lb_); \
    gload16(gA1 + off_, lwA1 + lb_); \
    gload16(gB0 + off_, lwB0 + lb_); \
    gload16(gB1 + off_, lwB1 + lb_); \
} while (0)

    float4v acc[4][4] = {};

    // prologue: stage iter 0 into buf0; __syncthreads drains vmcnt(0)
    STAGE(0, 0);
    __syncthreads();

    for (int j = 0; j < NITER; j++) {
        // issue next-tile loads FIRST (T3 recipe), then ds_read + MFMA
        if (j + 1 < NITER) STAGE((j + 1) & 1, j + 1);
        const unsigned short* aP = smemA + (j & 1) * 4096;
        const unsigned short* bP = smemB + (j & 1) * 4096;
        short8 af[4], bf[4];
#pragma unroll
        for (int s = 0; s < 4; s++) {
            af[s] = *(const short8*)(aP + aOff[s]);
            bf[s] = *(const short8*)(bP + bOff[s]);
        }
#pragma unroll
        for (int i = 0; i < 4; i++)
#pragma unroll
            for (int jj = 0; jj < 4; jj++)
                acc[i][jj] = __builtin_amdgcn_mfma_f32_16x16x32_bf16(af[i], bf[jj], acc[i][jj], 0, 0, 0);
        __syncthreads();   // drains vmcnt(0) (next stage) + lgkm; buf swap safe
    }
#undef STAGE

    // ---- fused epilogue: relu(h) @ W2[:,0:4], shuffle-reduce, atomicAdd ----
    float4v w2r[4];
    float   b1v[4];
#pragma unroll
    for (int ns = 0; ns < 4; ns++) {
        int n_g = n0 + wave_n + ns * 16 + lane15;
        w2r[ns] = *(const float4v*)(W2 + (size_t)n_g * 32);
        b1v[ns] = b1[n_g];
    }
#pragma unroll
    for (int ms = 0; ms < 4; ms++) {
        float p[4][4];
#pragma unroll
        for (int r = 0; r < 4; r++)
#pragma unroll
            for (int c = 0; c < 4; c++) p[r][c] = 0.f;
#pragma unroll
        for (int ns = 0; ns < 4; ns++) {
            float4v av = acc[ms][ns];
#pragma unroll
            for (int r = 0; r < 4; r++) {
                float h = av[r] + b1v[ns];
                h = h > 0.f ? h : 0.f;
                p[r][0] += h * w2r[ns][0];
                p[r][1] += h * w2r[ns][1];
                p[r][2] += h * w2r[ns][2];
                p[r][3] += h * w2r[ns][3];
            }
        }
#pragma unroll
        for (int off = 1; off < 16; off <<= 1)
#pragma unroll
            for (int r = 0; r < 4; r++)
#pragma unroll
                for (int c = 0; c < 4; c++)
                    p[r][c] += __shfl_xor(p[r][c], off);
        if (lane15 < 4) {
            int c = lane15;
#pragma unroll
            for (int r = 0; r < 4; r++) {
                int mg = m0 + wave_m + ms * 16 + quad * 4 + r;
                atomicAdd(&zbuf[(size_t)mg * 4 + c], p[r][c]);
            }
        }
    }
}

// ---- log-softmax gather + masked sum (unchanged) ----
__global__ __launch_bounds__(128) void reduce_logp_kernel(
        const float* __restrict__ zbuf,
        const int*   __restrict__ actions,
        const int*   __restrict__ lengths,
        const float* __restrict__ b2,
        float*       __restrict__ out)
{
    int b = blockIdx.x;
    int t = blockIdx.y * 128 + threadIdx.x;
    int len = lengths[b];
    float local = 0.f;
    if (t < MAXT && t < len) {
        int row = b * TP1 + t;
        float4v z = *(const float4v*)(zbuf + (size_t)row * 4);
        float z0 = z[0] + b2[0], z1 = z[1] + b2[1], z2 = z[2] + b2[2], z3 = z[3] + b2[3];
        float mx = fmaxf(fmaxf(z0, z1), fmaxf(z2, z3));
        float se = expf(z0 - mx) + expf(z1 - mx) + expf(z2 - mx) + expf(z3 - mx);
        int a = actions[b * MAXT + t];
        float za = (a == 0) ? z0 : (a == 1) ? z1 : (a == 2) ? z2 : z3;
        local = (za - mx) - logf(se);
    }
#pragma unroll
    for (int off = 32; off > 0; off >>= 1) local += __shfl_xor(local, off);
    __shared__ float wsum[2];
    if ((threadIdx.x & 63) == 0) wsum[threadIdx.x >> 6] = local;
    __syncthreads();
    if (threadIdx.x == 0) atomicAdd(out, -(wsum[0] + wsum[1]));   // out = -sum(logp)
}

extern "C" void kernel_launch(void* const* d_in, const int* in_sizes, int n_in,
                              void* d_out, int out_size, void* d_ws, size_t ws_size,
                              hipStream_t stream) {
    const float* s       = (const float*)d_in[0];  // (64,512,1024) fp32
    const int*   actions = (const int*)  d_in[1];  // (64,511)
    const int*   lengths = (const int*)  d_in[2];  // (64,)
    const float* W1      = (const float*)d_in[3];  // (1024,4096)
    const float* b1      = (const float*)d_in[4];  // (4096,)
    const float* W2      = (const float*)d_in[5];  // (4096,32)
    const float* b2      = (const float*)d_in[6];  // (32,)

    char* ws = (char*)d_ws;
    float*          zbuf = (float*)ws;             // [0, 512KB)
    unsigned short* Sb   = (unsigned short*)(ws + SBF_OFF);
    unsigned short* W1T  = (unsigned short*)(ws + W1T_OFF);

    hipMemsetAsync(ws, 0, ZBUF_BYTES, stream);
    hipMemsetAsync(d_out, 0, sizeof(float), stream);

    // merged pre-pass: s->bf16 (live rows, nt loads) + W1->W1T bf16
    prep_kernel<<<dim3(16384 + 4096), 256, 0, stream>>>(s, W1, lengths, Sb, W1T);
    // fused GEMM + relu + W2[:,0:4] projection (XCD-swizzled 1D grid)
    gemm_fused_kernel<<<dim3(8192), 256, 0, stream>>>(Sb, W1T, b1, W2, lengths, zbuf);
    // log-softmax gather + masked sum -> d_out
    reduce_logp_kernel<<<dim3(B_, 4), 128, 0, stream>>>(zbuf, actions, lengths, b2, (float*)d_out);
}